// Round 10
// baseline (409.015 us; speedup 1.0000x reference)
//
#include <hip/hip_runtime.h>
#include <hip/hip_bf16.h>
#include <stdint.h>
#include <stddef.h>

#define DI __device__ __forceinline__

typedef unsigned short u16;
typedef float f32x4 __attribute__((ext_vector_type(4)));
typedef short bf16x8 __attribute__((ext_vector_type(8)));
typedef u16 u16x4 __attribute__((ext_vector_type(4)));

constexpr int Mm = 8192;
constexpr int Dd = 1024;
constexpr float LOG2E = 1.44269504088896f;

DI u16 bf(float f) {
  __hip_bfloat16 h = __float2bfloat16(f);
  return *reinterpret_cast<u16*>(&h);
}

DI float b2f(short s) {
  union { float f; unsigned u; } v;
  v.u = ((unsigned)(unsigned short)s) << 16;
  return v.f;
}

DI f32x4 mfma16(bf16x8 a, bf16x8 b, f32x4 c) {
  return __builtin_amdgcn_mfma_f32_16x16x32_bf16(a, b, c, 0, 0, 0);
}

DI void gload16(const u16* g, u16* l) {
  __builtin_amdgcn_global_load_lds(
      (const __attribute__((address_space(1))) void*)(g),
      (__attribute__((address_space(3))) void*)(l), 16, 0, 0);
}

// ---------------- convert x (f32 -> bf16), 4 elems/thread ----------------
__global__ __launch_bounds__(256) void k_cvt(const float* __restrict__ x,
                                             u16* __restrict__ o) {
  size_t i = (size_t)blockIdx.x * 256 + threadIdx.x;
  float4 v = *(const float4*)(x + i * 4);
  u16x4 r;
  r.x = bf(v.x); r.y = bf(v.y); r.z = bf(v.z); r.w = bf(v.w);
  *(u16x4*)(o + i * 4) = r;
}

// ---------------- pb (f32) -> bf16 * LOG2E ----------------
__global__ __launch_bounds__(256) void k_pb(const float* __restrict__ pb,
                                            u16* __restrict__ pbb) {
  size_t i = (size_t)blockIdx.x * 256 + threadIdx.x;
  float4 v = *(const float4*)(pb + i * 4);
  u16x4 r;
  r.x = bf(v.x * LOG2E); r.y = bf(v.y * LOG2E);
  r.z = bf(v.z * LOG2E); r.w = bf(v.w * LOG2E);
  *(u16x4*)(pbb + i * 4) = r;
}

// ---------------- transpose 4x (1024x1024 f32 W -> bf16 WT[n][k]) ----------------
__global__ __launch_bounds__(256) void k_tr4(const float* __restrict__ W0,
                                             const float* __restrict__ W1,
                                             const float* __restrict__ W2,
                                             const float* __restrict__ W3,
                                             u16* __restrict__ T0,
                                             u16* __restrict__ T1,
                                             u16* __restrict__ T2,
                                             u16* __restrict__ T3) {
  __shared__ float t[32][33];
  const float* W;
  u16* T;
  switch (blockIdx.z) {
    case 0: W = W0; T = T0; break;
    case 1: W = W1; T = T1; break;
    case 2: W = W2; T = T2; break;
    default: W = W3; T = T3; break;
  }
  int bx = blockIdx.x * 32;  // k block
  int by = blockIdx.y * 32;  // n block
  int tx = threadIdx.x, ty = threadIdx.y;  // (32,8)
#pragma unroll
  for (int i = 0; i < 4; ++i)
    t[ty + i * 8][tx] = W[(size_t)(bx + ty + i * 8) * 1024 + by + tx];
  __syncthreads();
#pragma unroll
  for (int i = 0; i < 4; ++i)
    T[(size_t)(by + ty + i * 8) * 1024 + bx + tx] = bf(t[tx][ty + i * 8]);
}

// ---------------- GEMM (m97 structure): C[M,1024] = A @ WT^T ----------------
// MODE 0: Q  -> bf16 (acc+bias)*0.125*log2e, [m][d]
// MODE 1: K  -> bf16 acc+bias,               [m][d]
// MODE 2: V  -> bf16 acc+bias, transposed    [b][d][seq] (LDS-transposed store)
// MODE 3: O  -> f32 acc+bias+resid,          [m][d]
template <int MODE>
__global__ __launch_bounds__(256) void k_gemm(const u16* __restrict__ A,
                                              const u16* __restrict__ WT,
                                              const float* __restrict__ bias,
                                              const float* __restrict__ resid,
                                              void* __restrict__ outp) {
  __shared__ __align__(16) u16 smem[2 * 128 * 64];  // As | Bs, 32 KB
  u16* As = smem;
  u16* Bs = smem + 128 * 64;
  const int tid = threadIdx.x;
  const int lane = tid & 63;
  const int wave = tid >> 6;
  const int brow = blockIdx.y * 128;
  const int bcol = blockIdx.x * 128;
  const int wr = (wave >> 1) * 64;
  const int wc = (wave & 1) * 64;
  const int l15 = lane & 15, l4 = lane >> 4;

  f32x4 acc[4][4] = {};
  const int crow0 = tid >> 3;        // chunk row for r=0
  const int kpos = (tid & 7) * 8;    // k offset within row

  for (int t = 0; t < 16; ++t) {
    const int k0 = t * 64;
#pragma unroll
    for (int r = 0; r < 4; ++r) {
      int crow = r * 32 + crow0;
      u16* ldsbase_a = As + ((r * 256 + wave * 64) << 3);  // wave-uniform
      u16* ldsbase_b = Bs + ((r * 256 + wave * 64) << 3);
      gload16(A + (size_t)(brow + crow) * 1024 + k0 + kpos, ldsbase_a);
      gload16(WT + (size_t)(bcol + crow) * 1024 + k0 + kpos, ldsbase_b);
    }
    __syncthreads();
#pragma unroll
    for (int kk = 0; kk < 2; ++kk) {
      bf16x8 af[4], bg[4];
      const int kb = kk * 32 + l4 * 8;
#pragma unroll
      for (int mt = 0; mt < 4; ++mt)
        af[mt] = *(const bf16x8*)(As + (wr + mt * 16 + l15) * 64 + kb);
#pragma unroll
      for (int nt = 0; nt < 4; ++nt)
        bg[nt] = *(const bf16x8*)(Bs + (wc + nt * 16 + l15) * 64 + kb);
#pragma unroll
      for (int mt = 0; mt < 4; ++mt)
#pragma unroll
        for (int nt = 0; nt < 4; ++nt)
          acc[mt][nt] = mfma16(af[mt], bg[nt], acc[mt][nt]);
    }
    __syncthreads();
  }

  if (MODE == 2) {
    // transpose through LDS: [d_local 128][seq_local 128] bf16, XOR-swizzled
#pragma unroll
    for (int nt = 0; nt < 4; ++nt) {
      int dl = wc + nt * 16 + l15;
      float bv = bias[bcol + dl];
#pragma unroll
      for (int mt = 0; mt < 4; ++mt) {
        int s4 = wr + mt * 16 + l4 * 4;
        u16x4 pk;
        pk.x = bf(acc[mt][nt][0] + bv);
        pk.y = bf(acc[mt][nt][1] + bv);
        pk.z = bf(acc[mt][nt][2] + bv);
        pk.w = bf(acc[mt][nt][3] + bv);
        *(u16x4*)(smem + dl * 128 + (s4 ^ ((dl & 7) << 3))) = pk;
      }
    }
    __syncthreads();
    const int bb = brow >> 10;        // batch
    const int seq0 = brow & 1023;
    const int chunk = tid & 15;
#pragma unroll
    for (int p = 0; p < 8; ++p) {
      int dl = p * 16 + (tid >> 4);
      bf16x8 v = *(const bf16x8*)(smem + dl * 128 + ((chunk * 8) ^ ((dl & 7) << 3)));
      *(bf16x8*)((u16*)outp + ((size_t)bb * 1024 + bcol + dl) * 1024 + seq0 + chunk * 8) = v;
    }
    return;
  }

  // epilogue. C/D: col = lane&15, row = (lane>>4)*4 + i
#pragma unroll
  for (int nt = 0; nt < 4; ++nt) {
    int gc = bcol + wc + nt * 16 + l15;
    float bv = bias[gc];
#pragma unroll
    for (int mt = 0; mt < 4; ++mt) {
#pragma unroll
      for (int i = 0; i < 4; ++i) {
        int gm = brow + wr + mt * 16 + l4 * 4 + i;
        float v = acc[mt][nt][i] + bv;
        if (MODE == 0) {
          ((u16*)outp)[(size_t)gm * 1024 + gc] = bf(v * (0.125f * LOG2E));
        } else if (MODE == 1) {
          ((u16*)outp)[(size_t)gm * 1024 + gc] = bf(v);
        } else {
          ((float*)outp)[(size_t)gm * 1024 + gc] = v + resid[(size_t)gm * 1024 + gc];
        }
      }
    }
  }
}

// ---------------- attention v10: v9 with (a) plain (non-NT) attn_out stores,
// (b) V chunk-0 prefetch hidden under softmax ----------------
__global__ __launch_bounds__(256, 3) void k_attn(const u16* __restrict__ q,
                                                 const u16* __restrict__ kk_,
                                                 const u16* __restrict__ vt,
                                                 const u16* __restrict__ pbb,
                                                 float* __restrict__ attn_out,
                                                 u16* __restrict__ aout) {
  __shared__ __align__(16) u16 sc[16 * 1024];   // 32 KB scores/P, XOR-swizzled
  __shared__ __align__(16) u16 kst[4][2][1024]; // 16 KB: per-wave dbuf 2x2KB
  __shared__ float invbuf[16];
  const int tid = threadIdx.x;
  const int lane = tid & 63;
  const int wave = tid >> 6;        // 0..3
  const int bid = blockIdx.x;
  const int swz = (bid & 7) * 1024 + (bid >> 3);  // XCD-chunked (8192%8==0)
  const int bh = swz >> 6;          // 0..127
  const int q0 = (swz & 63) * 16;
  const int b = bh >> 4, h = bh & 15;
  const int l15 = lane & 15, l4 = lane >> 4;
  // staging lane map: instr i covers rows i*8+(lane>>3); slot lane&7 holds
  // global granule (lane&7)^(row&7)  [pre-swizzled source -> linear dest]
  const int srow8 = (lane >> 3) & 7;
  const int sgsw = (lane & 7) ^ srow8;
  u16* const kw = &kst[wave][0][0];
  const u16* vbase = vt + (size_t)(b * 1024 + h * 64 + wave * 16) * 1024 + sgsw * 8;

  // Q fragments (one 16-row group)
  bf16x8 qf0, qf1;
  {
    const u16* qp = q + ((size_t)(b * 1024 + q0 + l15)) * 1024 + h * 64 + l4 * 8;
    qf0 = *(const bf16x8*)qp;
    qf1 = *(const bf16x8*)(qp + 32);
  }

  // ---- P1: S = K.Q^T (raw) -> sc; wave-private kv quarter, 16 chunks of 16 ----
  {
    const int kvb = wave * 256;
    const u16* kbase = kk_ + (size_t)(b * 1024 + kvb) * 1024 + h * 64 + sgsw * 8;
    // prologue: chunk 0
    gload16(kbase + (size_t)srow8 * 1024, kw);
    gload16(kbase + (size_t)(8 + srow8) * 1024, kw + 512);
    for (int c = 0; c < 16; ++c) {
      if (c < 15) {
        const u16* nsrc = kbase + (size_t)((c + 1) * 16 + srow8) * 1024;
        u16* ndst = kw + ((c + 1) & 1) * 1024;
        gload16(nsrc, ndst);
        gload16(nsrc + 8 * 1024, ndst + 512);
        asm volatile("s_waitcnt vmcnt(2)" ::: "memory");
      } else {
        asm volatile("s_waitcnt vmcnt(0)" ::: "memory");
      }
      __builtin_amdgcn_sched_barrier(0);
      const u16* kb = kw + (c & 1) * 1024;
      const int r = l15;
      bf16x8 k0 = *(const bf16x8*)(kb + r * 64 + ((l4 ^ (r & 7)) << 3));
      bf16x8 k1 = *(const bf16x8*)(kb + r * 64 + (((4 + l4) ^ (r & 7)) << 3));
      f32x4 cc = {};
      cc = mfma16(k0, qf0, cc);
      cc = mfma16(k1, qf1, cc);
      // lane holds S[kv = kvb + c*16 + l4*4 + i][q-local = l15]
      const int c4 = kvb + c * 16 + l4 * 4;
      u16x4 pk;
      pk.x = bf(cc[0]); pk.y = bf(cc[1]); pk.z = bf(cc[2]); pk.w = bf(cc[3]);
      *(u16x4*)(sc + l15 * 1024 + (c4 ^ ((l15 & 7) << 3))) = pk;
    }
  }
  __syncthreads();   // sc complete (per-wave DMAs already drained)

  // prefetch V chunk 0 NOW: latency hides under softmax; the post-softmax
  // __syncthreads (vmcnt(0)) guarantees it's in LDS before P3 reads buf0.
  gload16(vbase + (size_t)srow8 * 1024, kw);
  gload16(vbase + (size_t)(8 + srow8) * 1024, kw + 512);

  // ---- P2: softmax + pbb add, 16 thr/row; unnormalized exp bf16 -> sc ----
  const int r2 = tid >> 4;
  const int l2 = tid & 15;
  {
    const int rx = (r2 & 7) << 3;
    u16* rowp = sc + r2 * 1024;
    const u16* pbrow = pbb + (size_t)(q0 + r2) * 1024 + l2 * 8;
    bf16x8 R[8];
#pragma unroll
    for (int g = 0; g < 8; ++g) {
      bf16x8 v = *(const bf16x8*)(rowp + ((g * 128 + l2 * 8) ^ rx));
      bf16x8 pv = *(const bf16x8*)(pbrow + g * 128);
      bf16x8 s;
#pragma unroll
      for (int j = 0; j < 8; ++j) s[j] = (short)bf(b2f(v[j]) + b2f(pv[j]));
      R[g] = s;
    }
    float mx = -3e38f;
#pragma unroll
    for (int g = 0; g < 8; ++g)
#pragma unroll
      for (int j = 0; j < 8; ++j) mx = fmaxf(mx, b2f(R[g][j]));
#pragma unroll
    for (int o = 1; o < 16; o <<= 1) mx = fmaxf(mx, __shfl_xor(mx, o));
    float sum = 0.f;
#pragma unroll
    for (int g = 0; g < 8; ++g) {
      bf16x8 e;
#pragma unroll
      for (int j = 0; j < 8; ++j) {
        float t = exp2f(b2f(R[g][j]) - mx);
        sum += t;
        e[j] = (short)bf(t);
      }
      *(bf16x8*)(rowp + ((g * 128 + l2 * 8) ^ rx)) = e;  // unnormalized exp
    }
#pragma unroll
    for (int o = 1; o < 16; o <<= 1) sum += __shfl_xor(sum, o);
    if (l2 == 0) invbuf[r2] = 1.f / sum;
  }
  __syncthreads();   // exp-P + invbuf visible; V0 drained into buf0

  // ---- P3: O = P.V^T; wave-private d 16-rows, 16 chunks of 64 kv ----
  f32x4 oacc = {};
  {
    for (int c = 0; c < 16; ++c) {
      if (c < 15) {
        const u16* nsrc = vbase + (size_t)srow8 * 1024 + (c + 1) * 64;
        u16* ndst = kw + ((c + 1) & 1) * 1024;
        gload16(nsrc, ndst);
        gload16(nsrc + 8 * 1024, ndst + 512);
        asm volatile("s_waitcnt vmcnt(2)" ::: "memory");
      } else {
        asm volatile("s_waitcnt vmcnt(0)" ::: "memory");
      }
      __builtin_amdgcn_sched_barrier(0);
      const u16* vb = kw + (c & 1) * 1024;
      const int vr = l15;
#pragma unroll
      for (int ks = 0; ks < 2; ++ks) {
        const int gg = ks * 4 + l4;
        bf16x8 vf = *(const bf16x8*)(vb + vr * 64 + ((gg ^ (vr & 7)) << 3));
        const int e = c * 64 + ks * 32 + l4 * 8;
        bf16x8 pf = *(const bf16x8*)(sc + l15 * 1024 + (e ^ ((l15 & 7) << 3)));
        oacc = mfma16(pf, vf, oacc);
      }
    }
  }

  // ---- tail: all global stores ----
#pragma unroll
  for (int i = 0; i < 4; ++i) {
    float iv = invbuf[l4 * 4 + i];
    aout[(size_t)(b * 1024 + q0 + l4 * 4 + i) * 1024 + h * 64 + wave * 16 + l15] =
        bf(oacc[i] * iv);
  }
  // attn_out: row it, col4 = tid -> 64 lanes x 16B = 1KB contiguous per instr.
  // Plain stores (L2 write-back aggregation, like fillBuffer's 6.7 TB/s path).
#pragma unroll
  for (int it = 0; it < 16; ++it) {
    const int ebase = (tid * 4) ^ ((it & 7) << 3);
    u16x4 p = *(const u16x4*)(sc + it * 1024 + ebase);
    const float iv = invbuf[it];
    f32x4 w;
    w[0] = b2f((short)p.x) * iv;
    w[1] = b2f((short)p.y) * iv;
    w[2] = b2f((short)p.z) * iv;
    w[3] = b2f((short)p.w) * iv;
    *(f32x4*)(attn_out + ((size_t)bh * 1024 + q0 + it) * 1024 + tid * 4) = w;
  }
}

// ---------------- LayerNorm: one wave per row ----------------
__global__ __launch_bounds__(256) void k_ln(const float* __restrict__ y,
                                            const float* __restrict__ g,
                                            const float* __restrict__ be,
                                            float* __restrict__ o) {
  const int lane = threadIdx.x & 63;
  const int wave = threadIdx.x >> 6;
  size_t row = (size_t)blockIdx.x * 4 + wave;
  const float* yr = y + row * 1024;
  float4 v[4];
  float s = 0.f, sq = 0.f;
#pragma unroll
  for (int i = 0; i < 4; ++i) {
    v[i] = *(const float4*)(yr + i * 256 + lane * 4);
    s += v[i].x + v[i].y + v[i].z + v[i].w;
    sq += v[i].x * v[i].x + v[i].y * v[i].y + v[i].z * v[i].z + v[i].w * v[i].w;
  }
#pragma unroll
  for (int off = 1; off < 64; off <<= 1) {
    s += __shfl_xor(s, off);
    sq += __shfl_xor(sq, off);
  }
  float mu = s * (1.f / 1024.f);
  float var = sq * (1.f / 1024.f) - mu * mu;
  float rs = rsqrtf(fmaxf(var, 0.f) + 1e-5f);
  float* orow = o + row * 1024;
#pragma unroll
  for (int i = 0; i < 4; ++i) {
    int c = i * 256 + lane * 4;
    float4 gg = *(const float4*)(g + c);
    float4 bb = *(const float4*)(be + c);
    float4 rr;
    rr.x = (v[i].x - mu) * rs * gg.x + bb.x;
    rr.y = (v[i].y - mu) * rs * gg.y + bb.y;
    rr.z = (v[i].z - mu) * rs * gg.z + bb.z;
    rr.w = (v[i].w - mu) * rs * gg.w + bb.w;
    *(float4*)(orow + c) = rr;
  }
}

extern "C" void kernel_launch(void* const* d_in, const int* in_sizes, int n_in,
                              void* d_out, int out_size, void* d_ws, size_t ws_size,
                              hipStream_t stream) {
  const float* x = (const float*)d_in[0];
  const float* Wq = (const float*)d_in[1];
  const float* bq = (const float*)d_in[2];
  const float* Wk = (const float*)d_in[3];
  const float* bk = (const float*)d_in[4];
  const float* Wv = (const float*)d_in[5];
  const float* bv = (const float*)d_in[6];
  const float* pb = (const float*)d_in[7];
  const float* Wo = (const float*)d_in[8];
  const float* bo = (const float*)d_in[9];
  const float* gamma = (const float*)d_in[10];
  const float* beta = (const float*)d_in[11];

  char* ws = (char*)d_ws;
  u16* xb = (u16*)(ws);            // 16MB, reused as aows after V gemm
  u16* aows = (u16*)(ws);
  u16* wqT = (u16*)(ws + (16u << 20));   // reused as pbb after Q gemm
  u16* pbb = (u16*)(ws + (16u << 20));
  u16* wkT = (u16*)(ws + (18u << 20));
  u16* wvT = (u16*)(ws + (20u << 20));
  u16* woT = (u16*)(ws + (22u << 20));
  u16* qws = (u16*)(ws + (24u << 20));
  u16* kws = (u16*)(ws + (40u << 20));
  u16* vtws = (u16*)(ws + (56u << 20));
  float* yws = (float*)(ws + (72u << 20));

  float* out_ln = (float*)d_out;
  float* out_attn = out_ln + (size_t)Mm * Dd;

  k_cvt<<<8192, 256, 0, stream>>>(x, xb);
  k_tr4<<<dim3(32, 32, 4), dim3(32, 8), 0, stream>>>(Wq, Wk, Wv, Wo, wqT, wkT, wvT, woT);
  k_gemm<0><<<dim3(8, 64), 256, 0, stream>>>(xb, wqT, bq, nullptr, qws);
  k_pb<<<1024, 256, 0, stream>>>(pb, pbb);   // overlays wqT (dead after Q gemm)
  k_gemm<1><<<dim3(8, 64), 256, 0, stream>>>(xb, wkT, bk, nullptr, kws);
  k_gemm<2><<<dim3(8, 64), 256, 0, stream>>>(xb, wvT, bv, nullptr, vtws);
  k_attn<<<8192, 256, 0, stream>>>(qws, kws, vtws, pbb, out_attn, aows);
  k_gemm<3><<<dim3(8, 64), 256, 0, stream>>>(aows, woT, bo, x, yws);
  k_ln<<<2048, 256, 0, stream>>>(yws, gamma, beta, out_ln);
}

// Round 11
// 315.076 us; speedup vs baseline: 1.2981x; 1.2981x over previous
//
#include <hip/hip_runtime.h>
#include <hip/hip_bf16.h>
#include <stdint.h>
#include <stddef.h>

#define DI __device__ __forceinline__

typedef unsigned short u16;
typedef float f32x4 __attribute__((ext_vector_type(4)));
typedef short bf16x8 __attribute__((ext_vector_type(8)));
typedef u16 u16x4 __attribute__((ext_vector_type(4)));

constexpr int Mm = 8192;
constexpr int Dd = 1024;
constexpr float LOG2E = 1.44269504088896f;

DI u16 bf(float f) {
  __hip_bfloat16 h = __float2bfloat16(f);
  return *reinterpret_cast<u16*>(&h);
}

DI float b2f(short s) {
  union { float f; unsigned u; } v;
  v.u = ((unsigned)(unsigned short)s) << 16;
  return v.f;
}

DI f32x4 mfma16(bf16x8 a, bf16x8 b, f32x4 c) {
  return __builtin_amdgcn_mfma_f32_16x16x32_bf16(a, b, c, 0, 0, 0);
}

DI void gload16(const u16* g, u16* l) {
  __builtin_amdgcn_global_load_lds(
      (const __attribute__((address_space(1))) void*)(g),
      (__attribute__((address_space(3))) void*)(l), 16, 0, 0);
}

// ---------------- convert x (f32 -> bf16), 4 elems/thread ----------------
__global__ __launch_bounds__(256) void k_cvt(const float* __restrict__ x,
                                             u16* __restrict__ o) {
  size_t i = (size_t)blockIdx.x * 256 + threadIdx.x;
  float4 v = *(const float4*)(x + i * 4);
  u16x4 r;
  r.x = bf(v.x); r.y = bf(v.y); r.z = bf(v.z); r.w = bf(v.w);
  *(u16x4*)(o + i * 4) = r;
}

// ---------------- pb (f32) -> bf16 * LOG2E ----------------
__global__ __launch_bounds__(256) void k_pb(const float* __restrict__ pb,
                                            u16* __restrict__ pbb) {
  size_t i = (size_t)blockIdx.x * 256 + threadIdx.x;
  float4 v = *(const float4*)(pb + i * 4);
  u16x4 r;
  r.x = bf(v.x * LOG2E); r.y = bf(v.y * LOG2E);
  r.z = bf(v.z * LOG2E); r.w = bf(v.w * LOG2E);
  *(u16x4*)(pbb + i * 4) = r;
}

// ---------------- transpose 4x (1024x1024 f32 W -> bf16 WT[n][k]) ----------------
__global__ __launch_bounds__(256) void k_tr4(const float* __restrict__ W0,
                                             const float* __restrict__ W1,
                                             const float* __restrict__ W2,
                                             const float* __restrict__ W3,
                                             u16* __restrict__ T0,
                                             u16* __restrict__ T1,
                                             u16* __restrict__ T2,
                                             u16* __restrict__ T3) {
  __shared__ float t[32][33];
  const float* W;
  u16* T;
  switch (blockIdx.z) {
    case 0: W = W0; T = T0; break;
    case 1: W = W1; T = T1; break;
    case 2: W = W2; T = T2; break;
    default: W = W3; T = T3; break;
  }
  int bx = blockIdx.x * 32;  // k block
  int by = blockIdx.y * 32;  // n block
  int tx = threadIdx.x, ty = threadIdx.y;  // (32,8)
#pragma unroll
  for (int i = 0; i < 4; ++i)
    t[ty + i * 8][tx] = W[(size_t)(bx + ty + i * 8) * 1024 + by + tx];
  __syncthreads();
#pragma unroll
  for (int i = 0; i < 4; ++i)
    T[(size_t)(by + ty + i * 8) * 1024 + bx + tx] = bf(t[tx][ty + i * 8]);
}

// ---------------- GEMM (m97 structure): C[M,1024] = A @ WT^T ----------------
// MODE 0: Q  -> bf16 (acc+bias)*0.125*log2e, [m][d]
// MODE 1: K  -> bf16 acc+bias,               [m][d]
// MODE 2: V  -> bf16 acc+bias, transposed    [b][d][seq] (LDS-transposed store)
// MODE 3: O  -> f32 acc+bias+resid,          [m][d]
template <int MODE>
__global__ __launch_bounds__(256) void k_gemm(const u16* __restrict__ A,
                                              const u16* __restrict__ WT,
                                              const float* __restrict__ bias,
                                              const float* __restrict__ resid,
                                              void* __restrict__ outp) {
  __shared__ __align__(16) u16 smem[2 * 128 * 64];  // As | Bs, 32 KB
  u16* As = smem;
  u16* Bs = smem + 128 * 64;
  const int tid = threadIdx.x;
  const int lane = tid & 63;
  const int wave = tid >> 6;
  const int brow = blockIdx.y * 128;
  const int bcol = blockIdx.x * 128;
  const int wr = (wave >> 1) * 64;
  const int wc = (wave & 1) * 64;
  const int l15 = lane & 15, l4 = lane >> 4;

  f32x4 acc[4][4] = {};
  const int crow0 = tid >> 3;        // chunk row for r=0
  const int kpos = (tid & 7) * 8;    // k offset within row

  for (int t = 0; t < 16; ++t) {
    const int k0 = t * 64;
#pragma unroll
    for (int r = 0; r < 4; ++r) {
      int crow = r * 32 + crow0;
      u16* ldsbase_a = As + ((r * 256 + wave * 64) << 3);  // wave-uniform
      u16* ldsbase_b = Bs + ((r * 256 + wave * 64) << 3);
      gload16(A + (size_t)(brow + crow) * 1024 + k0 + kpos, ldsbase_a);
      gload16(WT + (size_t)(bcol + crow) * 1024 + k0 + kpos, ldsbase_b);
    }
    __syncthreads();
#pragma unroll
    for (int kk = 0; kk < 2; ++kk) {
      bf16x8 af[4], bg[4];
      const int kb = kk * 32 + l4 * 8;
#pragma unroll
      for (int mt = 0; mt < 4; ++mt)
        af[mt] = *(const bf16x8*)(As + (wr + mt * 16 + l15) * 64 + kb);
#pragma unroll
      for (int nt = 0; nt < 4; ++nt)
        bg[nt] = *(const bf16x8*)(Bs + (wc + nt * 16 + l15) * 64 + kb);
#pragma unroll
      for (int mt = 0; mt < 4; ++mt)
#pragma unroll
        for (int nt = 0; nt < 4; ++nt)
          acc[mt][nt] = mfma16(af[mt], bg[nt], acc[mt][nt]);
    }
    __syncthreads();
  }

  if (MODE == 2) {
    // transpose through LDS: [d_local 128][seq_local 128] bf16, XOR-swizzled
#pragma unroll
    for (int nt = 0; nt < 4; ++nt) {
      int dl = wc + nt * 16 + l15;
      float bv = bias[bcol + dl];
#pragma unroll
      for (int mt = 0; mt < 4; ++mt) {
        int s4 = wr + mt * 16 + l4 * 4;
        u16x4 pk;
        pk.x = bf(acc[mt][nt][0] + bv);
        pk.y = bf(acc[mt][nt][1] + bv);
        pk.z = bf(acc[mt][nt][2] + bv);
        pk.w = bf(acc[mt][nt][3] + bv);
        *(u16x4*)(smem + dl * 128 + (s4 ^ ((dl & 7) << 3))) = pk;
      }
    }
    __syncthreads();
    const int bb = brow >> 10;        // batch
    const int seq0 = brow & 1023;
    const int chunk = tid & 15;
#pragma unroll
    for (int p = 0; p < 8; ++p) {
      int dl = p * 16 + (tid >> 4);
      bf16x8 v = *(const bf16x8*)(smem + dl * 128 + ((chunk * 8) ^ ((dl & 7) << 3)));
      *(bf16x8*)((u16*)outp + ((size_t)bb * 1024 + bcol + dl) * 1024 + seq0 + chunk * 8) = v;
    }
    return;
  }

  // epilogue. C/D: col = lane&15, row = (lane>>4)*4 + i
#pragma unroll
  for (int nt = 0; nt < 4; ++nt) {
    int gc = bcol + wc + nt * 16 + l15;
    float bv = bias[gc];
#pragma unroll
    for (int mt = 0; mt < 4; ++mt) {
#pragma unroll
      for (int i = 0; i < 4; ++i) {
        int gm = brow + wr + mt * 16 + l4 * 4 + i;
        float v = acc[mt][nt][i] + bv;
        if (MODE == 0) {
          ((u16*)outp)[(size_t)gm * 1024 + gc] = bf(v * (0.125f * LOG2E));
        } else if (MODE == 1) {
          ((u16*)outp)[(size_t)gm * 1024 + gc] = bf(v);
        } else {
          ((float*)outp)[(size_t)gm * 1024 + gc] = v + resid[(size_t)gm * 1024 + gc];
        }
      }
    }
  }
}

// ---------------- attention v11: v9 structure + V0 prefetch under softmax;
// attn_out via NONTEMPORAL full-line stores (v10 A/B proved NT is required:
// plain stores thrash L2 with the 512MB stream, +94us) ----------------
__global__ __launch_bounds__(256, 3) void k_attn(const u16* __restrict__ q,
                                                 const u16* __restrict__ kk_,
                                                 const u16* __restrict__ vt,
                                                 const u16* __restrict__ pbb,
                                                 float* __restrict__ attn_out,
                                                 u16* __restrict__ aout) {
  __shared__ __align__(16) u16 sc[16 * 1024];   // 32 KB scores/P, XOR-swizzled
  __shared__ __align__(16) u16 kst[4][2][1024]; // 16 KB: per-wave dbuf 2x2KB
  __shared__ float invbuf[16];
  const int tid = threadIdx.x;
  const int lane = tid & 63;
  const int wave = tid >> 6;        // 0..3
  const int bid = blockIdx.x;
  const int swz = (bid & 7) * 1024 + (bid >> 3);  // XCD-chunked (8192%8==0)
  const int bh = swz >> 6;          // 0..127
  const int q0 = (swz & 63) * 16;
  const int b = bh >> 4, h = bh & 15;
  const int l15 = lane & 15, l4 = lane >> 4;
  // staging lane map: instr i covers rows i*8+(lane>>3); slot lane&7 holds
  // global granule (lane&7)^(row&7)  [pre-swizzled source -> linear dest]
  const int srow8 = (lane >> 3) & 7;
  const int sgsw = (lane & 7) ^ srow8;
  u16* const kw = &kst[wave][0][0];
  const u16* vbase = vt + (size_t)(b * 1024 + h * 64 + wave * 16) * 1024 + sgsw * 8;

  // Q fragments (one 16-row group)
  bf16x8 qf0, qf1;
  {
    const u16* qp = q + ((size_t)(b * 1024 + q0 + l15)) * 1024 + h * 64 + l4 * 8;
    qf0 = *(const bf16x8*)qp;
    qf1 = *(const bf16x8*)(qp + 32);
  }

  // ---- P1: S = K.Q^T (raw) -> sc; wave-private kv quarter, 16 chunks of 16 ----
  {
    const int kvb = wave * 256;
    const u16* kbase = kk_ + (size_t)(b * 1024 + kvb) * 1024 + h * 64 + sgsw * 8;
    // prologue: chunk 0
    gload16(kbase + (size_t)srow8 * 1024, kw);
    gload16(kbase + (size_t)(8 + srow8) * 1024, kw + 512);
    for (int c = 0; c < 16; ++c) {
      if (c < 15) {
        const u16* nsrc = kbase + (size_t)((c + 1) * 16 + srow8) * 1024;
        u16* ndst = kw + ((c + 1) & 1) * 1024;
        gload16(nsrc, ndst);
        gload16(nsrc + 8 * 1024, ndst + 512);
        asm volatile("s_waitcnt vmcnt(2)" ::: "memory");
      } else {
        asm volatile("s_waitcnt vmcnt(0)" ::: "memory");
      }
      __builtin_amdgcn_sched_barrier(0);
      const u16* kb = kw + (c & 1) * 1024;
      const int r = l15;
      bf16x8 k0 = *(const bf16x8*)(kb + r * 64 + ((l4 ^ (r & 7)) << 3));
      bf16x8 k1 = *(const bf16x8*)(kb + r * 64 + (((4 + l4) ^ (r & 7)) << 3));
      f32x4 cc = {};
      cc = mfma16(k0, qf0, cc);
      cc = mfma16(k1, qf1, cc);
      // lane holds S[kv = kvb + c*16 + l4*4 + i][q-local = l15]
      const int c4 = kvb + c * 16 + l4 * 4;
      u16x4 pk;
      pk.x = bf(cc[0]); pk.y = bf(cc[1]); pk.z = bf(cc[2]); pk.w = bf(cc[3]);
      *(u16x4*)(sc + l15 * 1024 + (c4 ^ ((l15 & 7) << 3))) = pk;
    }
  }
  __syncthreads();   // sc complete (per-wave DMAs already drained)

  // prefetch V chunk 0 NOW: latency hides under softmax; the post-softmax
  // __syncthreads (vmcnt(0)) guarantees it's in LDS before P3 reads buf0.
  gload16(vbase + (size_t)srow8 * 1024, kw);
  gload16(vbase + (size_t)(8 + srow8) * 1024, kw + 512);

  // ---- P2: softmax + pbb add, 16 thr/row; unnormalized exp bf16 -> sc ----
  const int r2 = tid >> 4;
  const int l2 = tid & 15;
  {
    const int rx = (r2 & 7) << 3;
    u16* rowp = sc + r2 * 1024;
    const u16* pbrow = pbb + (size_t)(q0 + r2) * 1024 + l2 * 8;
    bf16x8 R[8];
#pragma unroll
    for (int g = 0; g < 8; ++g) {
      bf16x8 v = *(const bf16x8*)(rowp + ((g * 128 + l2 * 8) ^ rx));
      bf16x8 pv = *(const bf16x8*)(pbrow + g * 128);
      bf16x8 s;
#pragma unroll
      for (int j = 0; j < 8; ++j) s[j] = (short)bf(b2f(v[j]) + b2f(pv[j]));
      R[g] = s;
    }
    float mx = -3e38f;
#pragma unroll
    for (int g = 0; g < 8; ++g)
#pragma unroll
      for (int j = 0; j < 8; ++j) mx = fmaxf(mx, b2f(R[g][j]));
#pragma unroll
    for (int o = 1; o < 16; o <<= 1) mx = fmaxf(mx, __shfl_xor(mx, o));
    float sum = 0.f;
#pragma unroll
    for (int g = 0; g < 8; ++g) {
      bf16x8 e;
#pragma unroll
      for (int j = 0; j < 8; ++j) {
        float t = exp2f(b2f(R[g][j]) - mx);
        sum += t;
        e[j] = (short)bf(t);
      }
      *(bf16x8*)(rowp + ((g * 128 + l2 * 8) ^ rx)) = e;  // unnormalized exp
    }
#pragma unroll
    for (int o = 1; o < 16; o <<= 1) sum += __shfl_xor(sum, o);
    if (l2 == 0) invbuf[r2] = 1.f / sum;
  }
  __syncthreads();   // exp-P + invbuf visible; V0 drained into buf0

  // ---- P3: O = P.V^T; wave-private d 16-rows, 16 chunks of 64 kv ----
  f32x4 oacc = {};
  {
    for (int c = 0; c < 16; ++c) {
      if (c < 15) {
        const u16* nsrc = vbase + (size_t)srow8 * 1024 + (c + 1) * 64;
        u16* ndst = kw + ((c + 1) & 1) * 1024;
        gload16(nsrc, ndst);
        gload16(nsrc + 8 * 1024, ndst + 512);
        asm volatile("s_waitcnt vmcnt(2)" ::: "memory");
      } else {
        asm volatile("s_waitcnt vmcnt(0)" ::: "memory");
      }
      __builtin_amdgcn_sched_barrier(0);
      const u16* vb = kw + (c & 1) * 1024;
      const int vr = l15;
#pragma unroll
      for (int ks = 0; ks < 2; ++ks) {
        const int gg = ks * 4 + l4;
        bf16x8 vf = *(const bf16x8*)(vb + vr * 64 + ((gg ^ (vr & 7)) << 3));
        const int e = c * 64 + ks * 32 + l4 * 8;
        bf16x8 pf = *(const bf16x8*)(sc + l15 * 1024 + (e ^ ((l15 & 7) << 3)));
        oacc = mfma16(pf, vf, oacc);
      }
    }
  }

  // ---- tail: all global stores ----
#pragma unroll
  for (int i = 0; i < 4; ++i) {
    float iv = invbuf[l4 * 4 + i];
    aout[(size_t)(b * 1024 + q0 + l4 * 4 + i) * 1024 + h * 64 + wave * 16 + l15] =
        bf(oacc[i] * iv);
  }
  // attn_out: row it, col4 = tid -> 64 lanes x 16B = 1KB contiguous per instr.
  // NONTEMPORAL: keeps the 512MB stream out of L2 (v10 A/B: plain = +94us).
#pragma unroll
  for (int it = 0; it < 16; ++it) {
    const int ebase = (tid * 4) ^ ((it & 7) << 3);
    u16x4 p = *(const u16x4*)(sc + it * 1024 + ebase);
    const float iv = invbuf[it];
    f32x4 w;
    w[0] = b2f((short)p.x) * iv;
    w[1] = b2f((short)p.y) * iv;
    w[2] = b2f((short)p.z) * iv;
    w[3] = b2f((short)p.w) * iv;
    __builtin_nontemporal_store(
        w, (f32x4*)(attn_out + ((size_t)bh * 1024 + q0 + it) * 1024 + tid * 4));
  }
}

// ---------------- LayerNorm: one wave per row ----------------
__global__ __launch_bounds__(256) void k_ln(const float* __restrict__ y,
                                            const float* __restrict__ g,
                                            const float* __restrict__ be,
                                            float* __restrict__ o) {
  const int lane = threadIdx.x & 63;
  const int wave = threadIdx.x >> 6;
  size_t row = (size_t)blockIdx.x * 4 + wave;
  const float* yr = y + row * 1024;
  float4 v[4];
  float s = 0.f, sq = 0.f;
#pragma unroll
  for (int i = 0; i < 4; ++i) {
    v[i] = *(const float4*)(yr + i * 256 + lane * 4);
    s += v[i].x + v[i].y + v[i].z + v[i].w;
    sq += v[i].x * v[i].x + v[i].y * v[i].y + v[i].z * v[i].z + v[i].w * v[i].w;
  }
#pragma unroll
  for (int off = 1; off < 64; off <<= 1) {
    s += __shfl_xor(s, off);
    sq += __shfl_xor(sq, off);
  }
  float mu = s * (1.f / 1024.f);
  float var = sq * (1.f / 1024.f) - mu * mu;
  float rs = rsqrtf(fmaxf(var, 0.f) + 1e-5f);
  float* orow = o + row * 1024;
#pragma unroll
  for (int i = 0; i < 4; ++i) {
    int c = i * 256 + lane * 4;
    float4 gg = *(const float4*)(g + c);
    float4 bb = *(const float4*)(be + c);
    float4 rr;
    rr.x = (v[i].x - mu) * rs * gg.x + bb.x;
    rr.y = (v[i].y - mu) * rs * gg.y + bb.y;
    rr.z = (v[i].z - mu) * rs * gg.z + bb.z;
    rr.w = (v[i].w - mu) * rs * gg.w + bb.w;
    *(float4*)(orow + c) = rr;
  }
}

extern "C" void kernel_launch(void* const* d_in, const int* in_sizes, int n_in,
                              void* d_out, int out_size, void* d_ws, size_t ws_size,
                              hipStream_t stream) {
  const float* x = (const float*)d_in[0];
  const float* Wq = (const float*)d_in[1];
  const float* bq = (const float*)d_in[2];
  const float* Wk = (const float*)d_in[3];
  const float* bk = (const float*)d_in[4];
  const float* Wv = (const float*)d_in[5];
  const float* bv = (const float*)d_in[6];
  const float* pb = (const float*)d_in[7];
  const float* Wo = (const float*)d_in[8];
  const float* bo = (const float*)d_in[9];
  const float* gamma = (const float*)d_in[10];
  const float* beta = (const float*)d_in[11];

  char* ws = (char*)d_ws;
  u16* xb = (u16*)(ws);            // 16MB, reused as aows after V gemm
  u16* aows = (u16*)(ws);
  u16* wqT = (u16*)(ws + (16u << 20));   // reused as pbb after Q gemm
  u16* pbb = (u16*)(ws + (16u << 20));
  u16* wkT = (u16*)(ws + (18u << 20));
  u16* wvT = (u16*)(ws + (20u << 20));
  u16* woT = (u16*)(ws + (22u << 20));
  u16* qws = (u16*)(ws + (24u << 20));
  u16* kws = (u16*)(ws + (40u << 20));
  u16* vtws = (u16*)(ws + (56u << 20));
  float* yws = (float*)(ws + (72u << 20));

  float* out_ln = (float*)d_out;
  float* out_attn = out_ln + (size_t)Mm * Dd;

  k_cvt<<<8192, 256, 0, stream>>>(x, xb);
  k_tr4<<<dim3(32, 32, 4), dim3(32, 8), 0, stream>>>(Wq, Wk, Wv, Wo, wqT, wkT, wvT, woT);
  k_gemm<0><<<dim3(8, 64), 256, 0, stream>>>(xb, wqT, bq, nullptr, qws);
  k_pb<<<1024, 256, 0, stream>>>(pb, pbb);   // overlays wqT (dead after Q gemm)
  k_gemm<1><<<dim3(8, 64), 256, 0, stream>>>(xb, wkT, bk, nullptr, kws);
  k_gemm<2><<<dim3(8, 64), 256, 0, stream>>>(xb, wvT, bv, nullptr, vtws);
  k_attn<<<8192, 256, 0, stream>>>(qws, kws, vtws, pbb, out_attn, aows);
  k_gemm<3><<<dim3(8, 64), 256, 0, stream>>>(aows, woT, bo, x, yws);
  k_ln<<<2048, 256, 0, stream>>>(yws, gamma, beta, out_ln);
}

// Round 12
// 312.247 us; speedup vs baseline: 1.3099x; 1.0091x over previous
//
#include <hip/hip_runtime.h>
#include <hip/hip_bf16.h>
#include <stdint.h>
#include <stddef.h>

#define DI __device__ __forceinline__

typedef unsigned short u16;
typedef float f32x4 __attribute__((ext_vector_type(4)));
typedef short bf16x8 __attribute__((ext_vector_type(8)));
typedef u16 u16x4 __attribute__((ext_vector_type(4)));

constexpr int Mm = 8192;
constexpr int Dd = 1024;
constexpr float LOG2E = 1.44269504088896f;

DI u16 bf(float f) {
  __hip_bfloat16 h = __float2bfloat16(f);
  return *reinterpret_cast<u16*>(&h);
}

DI float b2f(short s) {
  union { float f; unsigned u; } v;
  v.u = ((unsigned)(unsigned short)s) << 16;
  return v.f;
}

DI f32x4 mfma16(bf16x8 a, bf16x8 b, f32x4 c) {
  return __builtin_amdgcn_mfma_f32_16x16x32_bf16(a, b, c, 0, 0, 0);
}

DI void gload16(const u16* g, u16* l) {
  __builtin_amdgcn_global_load_lds(
      (const __attribute__((address_space(1))) void*)(g),
      (__attribute__((address_space(3))) void*)(l), 16, 0, 0);
}

// ---------------- prep: cvt x | pb->bf16*log2e | transpose 4 W ----------------
// grid: [0,8192) cvt, [8192,9216) pb, [9216,13312) tr (z = (bid-9216)>>10)
__global__ __launch_bounds__(256) void k_prep(const float* __restrict__ x,
                                              u16* __restrict__ xb,
                                              const float* __restrict__ pb,
                                              u16* __restrict__ pbb,
                                              const float* __restrict__ W0,
                                              const float* __restrict__ W1,
                                              const float* __restrict__ W2,
                                              const float* __restrict__ W3,
                                              u16* __restrict__ T0,
                                              u16* __restrict__ T1,
                                              u16* __restrict__ T2,
                                              u16* __restrict__ T3) {
  __shared__ float t[32][33];
  const int bid = blockIdx.x;
  const int tid = threadIdx.x;
  if (bid < 8192) {
    size_t i = (size_t)bid * 256 + tid;
    float4 v = *(const float4*)(x + i * 4);
    u16x4 r;
    r.x = bf(v.x); r.y = bf(v.y); r.z = bf(v.z); r.w = bf(v.w);
    *(u16x4*)(xb + i * 4) = r;
  } else if (bid < 9216) {
    size_t i = (size_t)(bid - 8192) * 256 + tid;
    float4 v = *(const float4*)(pb + i * 4);
    u16x4 r;
    r.x = bf(v.x * LOG2E); r.y = bf(v.y * LOG2E);
    r.z = bf(v.z * LOG2E); r.w = bf(v.w * LOG2E);
    *(u16x4*)(pbb + i * 4) = r;
  } else {
    const int tt = bid - 9216;
    const int z = tt >> 10;
    const int rem = tt & 1023;
    const float* W;
    u16* T;
    switch (z) {
      case 0: W = W0; T = T0; break;
      case 1: W = W1; T = T1; break;
      case 2: W = W2; T = T2; break;
      default: W = W3; T = T3; break;
    }
    const int bx = (rem & 31) * 32;   // k block
    const int by = (rem >> 5) * 32;   // n block
    const int tx = tid & 31, ty = tid >> 5;  // (32,8)
#pragma unroll
    for (int i = 0; i < 4; ++i)
      t[ty + i * 8][tx] = W[(size_t)(bx + ty + i * 8) * 1024 + by + tx];
    __syncthreads();
#pragma unroll
    for (int i = 0; i < 4; ++i)
      T[(size_t)(by + ty + i * 8) * 1024 + bx + tx] = bf(t[tx][ty + i * 8]);
  }
}

// ---------------- QKV mega-GEMM: z=0 Q, z=1 K, z=2 V(transposed) ----------------
__global__ __launch_bounds__(256) void k_gemm_qkv(const u16* __restrict__ A,
                                                  const u16* __restrict__ wqT,
                                                  const u16* __restrict__ wkT,
                                                  const u16* __restrict__ wvT,
                                                  const float* __restrict__ bq,
                                                  const float* __restrict__ bk,
                                                  const float* __restrict__ bv,
                                                  u16* __restrict__ qo,
                                                  u16* __restrict__ ko,
                                                  u16* __restrict__ vo) {
  __shared__ __align__(16) u16 smem[2 * 128 * 64];  // As | Bs, 32 KB
  u16* As = smem;
  u16* Bs = smem + 128 * 64;
  const int mode = blockIdx.z;
  const u16* WT = mode == 0 ? wqT : (mode == 1 ? wkT : wvT);
  const float* bias = mode == 0 ? bq : (mode == 1 ? bk : bv);
  const int tid = threadIdx.x;
  const int lane = tid & 63;
  const int wave = tid >> 6;
  const int brow = blockIdx.y * 128;
  const int bcol = blockIdx.x * 128;
  const int wr = (wave >> 1) * 64;
  const int wc = (wave & 1) * 64;
  const int l15 = lane & 15, l4 = lane >> 4;

  f32x4 acc[4][4] = {};
  const int crow0 = tid >> 3;
  const int kpos = (tid & 7) * 8;

  for (int t = 0; t < 16; ++t) {
    const int k0 = t * 64;
#pragma unroll
    for (int r = 0; r < 4; ++r) {
      int crow = r * 32 + crow0;
      u16* ldsbase_a = As + ((r * 256 + wave * 64) << 3);
      u16* ldsbase_b = Bs + ((r * 256 + wave * 64) << 3);
      gload16(A + (size_t)(brow + crow) * 1024 + k0 + kpos, ldsbase_a);
      gload16(WT + (size_t)(bcol + crow) * 1024 + k0 + kpos, ldsbase_b);
    }
    __syncthreads();
#pragma unroll
    for (int kk = 0; kk < 2; ++kk) {
      bf16x8 af[4], bg[4];
      const int kb = kk * 32 + l4 * 8;
#pragma unroll
      for (int mt = 0; mt < 4; ++mt)
        af[mt] = *(const bf16x8*)(As + (wr + mt * 16 + l15) * 64 + kb);
#pragma unroll
      for (int nt = 0; nt < 4; ++nt)
        bg[nt] = *(const bf16x8*)(Bs + (wc + nt * 16 + l15) * 64 + kb);
#pragma unroll
      for (int mt = 0; mt < 4; ++mt)
#pragma unroll
        for (int nt = 0; nt < 4; ++nt)
          acc[mt][nt] = mfma16(af[mt], bg[nt], acc[mt][nt]);
    }
    __syncthreads();
  }

  if (mode == 2) {
    // V: transpose through LDS -> vo[b][d][seq]
#pragma unroll
    for (int nt = 0; nt < 4; ++nt) {
      int dl = wc + nt * 16 + l15;
      float bvv = bias[bcol + dl];
#pragma unroll
      for (int mt = 0; mt < 4; ++mt) {
        int s4 = wr + mt * 16 + l4 * 4;
        u16x4 pk;
        pk.x = bf(acc[mt][nt][0] + bvv);
        pk.y = bf(acc[mt][nt][1] + bvv);
        pk.z = bf(acc[mt][nt][2] + bvv);
        pk.w = bf(acc[mt][nt][3] + bvv);
        *(u16x4*)(smem + dl * 128 + (s4 ^ ((dl & 7) << 3))) = pk;
      }
    }
    __syncthreads();
    const int bb = brow >> 10;
    const int seq0 = brow & 1023;
    const int chunk = tid & 15;
#pragma unroll
    for (int p = 0; p < 8; ++p) {
      int dl = p * 16 + (tid >> 4);
      bf16x8 v = *(const bf16x8*)(smem + dl * 128 + ((chunk * 8) ^ ((dl & 7) << 3)));
      *(bf16x8*)(vo + ((size_t)bb * 1024 + bcol + dl) * 1024 + seq0 + chunk * 8) = v;
    }
    return;
  }

  u16* outp = mode == 0 ? qo : ko;
  const float scale = mode == 0 ? (0.125f * LOG2E) : 1.0f;
#pragma unroll
  for (int nt = 0; nt < 4; ++nt) {
    int gc = bcol + wc + nt * 16 + l15;
    float bvv = bias[gc];
#pragma unroll
    for (int mt = 0; mt < 4; ++mt) {
#pragma unroll
      for (int i = 0; i < 4; ++i) {
        int gm = brow + wr + mt * 16 + l4 * 4 + i;
        outp[(size_t)gm * 1024 + gc] = bf((acc[mt][nt][i] + bvv) * scale);
      }
    }
  }
}

// ---------------- O-proj GEMM: f32 acc+bias+resid ----------------
__global__ __launch_bounds__(256) void k_gemm_o(const u16* __restrict__ A,
                                                const u16* __restrict__ WT,
                                                const float* __restrict__ bias,
                                                const float* __restrict__ resid,
                                                float* __restrict__ outp) {
  __shared__ __align__(16) u16 smem[2 * 128 * 64];
  u16* As = smem;
  u16* Bs = smem + 128 * 64;
  const int tid = threadIdx.x;
  const int lane = tid & 63;
  const int wave = tid >> 6;
  const int brow = blockIdx.y * 128;
  const int bcol = blockIdx.x * 128;
  const int wr = (wave >> 1) * 64;
  const int wc = (wave & 1) * 64;
  const int l15 = lane & 15, l4 = lane >> 4;

  f32x4 acc[4][4] = {};
  const int crow0 = tid >> 3;
  const int kpos = (tid & 7) * 8;

  for (int t = 0; t < 16; ++t) {
    const int k0 = t * 64;
#pragma unroll
    for (int r = 0; r < 4; ++r) {
      int crow = r * 32 + crow0;
      u16* ldsbase_a = As + ((r * 256 + wave * 64) << 3);
      u16* ldsbase_b = Bs + ((r * 256 + wave * 64) << 3);
      gload16(A + (size_t)(brow + crow) * 1024 + k0 + kpos, ldsbase_a);
      gload16(WT + (size_t)(bcol + crow) * 1024 + k0 + kpos, ldsbase_b);
    }
    __syncthreads();
#pragma unroll
    for (int kk = 0; kk < 2; ++kk) {
      bf16x8 af[4], bg[4];
      const int kb = kk * 32 + l4 * 8;
#pragma unroll
      for (int mt = 0; mt < 4; ++mt)
        af[mt] = *(const bf16x8*)(As + (wr + mt * 16 + l15) * 64 + kb);
#pragma unroll
      for (int nt = 0; nt < 4; ++nt)
        bg[nt] = *(const bf16x8*)(Bs + (wc + nt * 16 + l15) * 64 + kb);
#pragma unroll
      for (int mt = 0; mt < 4; ++mt)
#pragma unroll
        for (int nt = 0; nt < 4; ++nt)
          acc[mt][nt] = mfma16(af[mt], bg[nt], acc[mt][nt]);
    }
    __syncthreads();
  }

#pragma unroll
  for (int nt = 0; nt < 4; ++nt) {
    int gc = bcol + wc + nt * 16 + l15;
    float bvv = bias[gc];
#pragma unroll
    for (int mt = 0; mt < 4; ++mt) {
#pragma unroll
      for (int i = 0; i < 4; ++i) {
        int gm = brow + wr + mt * 16 + l4 * 4 + i;
        outp[(size_t)gm * 1024 + gc] =
            acc[mt][nt][i] + bvv + resid[(size_t)gm * 1024 + gc];
      }
    }
  }
}

// ---------------- attention v11 (unchanged): wave-private counted-vmcnt ----------------
__global__ __launch_bounds__(256, 3) void k_attn(const u16* __restrict__ q,
                                                 const u16* __restrict__ kk_,
                                                 const u16* __restrict__ vt,
                                                 const u16* __restrict__ pbb,
                                                 float* __restrict__ attn_out,
                                                 u16* __restrict__ aout) {
  __shared__ __align__(16) u16 sc[16 * 1024];   // 32 KB scores/P, XOR-swizzled
  __shared__ __align__(16) u16 kst[4][2][1024]; // 16 KB: per-wave dbuf 2x2KB
  __shared__ float invbuf[16];
  const int tid = threadIdx.x;
  const int lane = tid & 63;
  const int wave = tid >> 6;        // 0..3
  const int bid = blockIdx.x;
  const int swz = (bid & 7) * 1024 + (bid >> 3);  // XCD-chunked (8192%8==0)
  const int bh = swz >> 6;          // 0..127
  const int q0 = (swz & 63) * 16;
  const int b = bh >> 4, h = bh & 15;
  const int l15 = lane & 15, l4 = lane >> 4;
  const int srow8 = (lane >> 3) & 7;
  const int sgsw = (lane & 7) ^ srow8;
  u16* const kw = &kst[wave][0][0];
  const u16* vbase = vt + (size_t)(b * 1024 + h * 64 + wave * 16) * 1024 + sgsw * 8;

  bf16x8 qf0, qf1;
  {
    const u16* qp = q + ((size_t)(b * 1024 + q0 + l15)) * 1024 + h * 64 + l4 * 8;
    qf0 = *(const bf16x8*)qp;
    qf1 = *(const bf16x8*)(qp + 32);
  }

  // ---- P1: S = K.Q^T -> sc; wave-private kv quarter, 16 chunks of 16 ----
  {
    const int kvb = wave * 256;
    const u16* kbase = kk_ + (size_t)(b * 1024 + kvb) * 1024 + h * 64 + sgsw * 8;
    gload16(kbase + (size_t)srow8 * 1024, kw);
    gload16(kbase + (size_t)(8 + srow8) * 1024, kw + 512);
    for (int c = 0; c < 16; ++c) {
      if (c < 15) {
        const u16* nsrc = kbase + (size_t)((c + 1) * 16 + srow8) * 1024;
        u16* ndst = kw + ((c + 1) & 1) * 1024;
        gload16(nsrc, ndst);
        gload16(nsrc + 8 * 1024, ndst + 512);
        asm volatile("s_waitcnt vmcnt(2)" ::: "memory");
      } else {
        asm volatile("s_waitcnt vmcnt(0)" ::: "memory");
      }
      __builtin_amdgcn_sched_barrier(0);
      const u16* kb = kw + (c & 1) * 1024;
      const int r = l15;
      bf16x8 k0 = *(const bf16x8*)(kb + r * 64 + ((l4 ^ (r & 7)) << 3));
      bf16x8 k1 = *(const bf16x8*)(kb + r * 64 + (((4 + l4) ^ (r & 7)) << 3));
      f32x4 cc = {};
      cc = mfma16(k0, qf0, cc);
      cc = mfma16(k1, qf1, cc);
      const int c4 = kvb + c * 16 + l4 * 4;
      u16x4 pk;
      pk.x = bf(cc[0]); pk.y = bf(cc[1]); pk.z = bf(cc[2]); pk.w = bf(cc[3]);
      *(u16x4*)(sc + l15 * 1024 + (c4 ^ ((l15 & 7) << 3))) = pk;
    }
  }
  __syncthreads();

  // prefetch V chunk 0 (drains at post-softmax barrier)
  gload16(vbase + (size_t)srow8 * 1024, kw);
  gload16(vbase + (size_t)(8 + srow8) * 1024, kw + 512);

  // ---- P2: softmax + pbb add ----
  const int r2 = tid >> 4;
  const int l2 = tid & 15;
  {
    const int rx = (r2 & 7) << 3;
    u16* rowp = sc + r2 * 1024;
    const u16* pbrow = pbb + (size_t)(q0 + r2) * 1024 + l2 * 8;
    bf16x8 R[8];
#pragma unroll
    for (int g = 0; g < 8; ++g) {
      bf16x8 v = *(const bf16x8*)(rowp + ((g * 128 + l2 * 8) ^ rx));
      bf16x8 pv = *(const bf16x8*)(pbrow + g * 128);
      bf16x8 s;
#pragma unroll
      for (int j = 0; j < 8; ++j) s[j] = (short)bf(b2f(v[j]) + b2f(pv[j]));
      R[g] = s;
    }
    float mx = -3e38f;
#pragma unroll
    for (int g = 0; g < 8; ++g)
#pragma unroll
      for (int j = 0; j < 8; ++j) mx = fmaxf(mx, b2f(R[g][j]));
#pragma unroll
    for (int o = 1; o < 16; o <<= 1) mx = fmaxf(mx, __shfl_xor(mx, o));
    float sum = 0.f;
#pragma unroll
    for (int g = 0; g < 8; ++g) {
      bf16x8 e;
#pragma unroll
      for (int j = 0; j < 8; ++j) {
        float t = exp2f(b2f(R[g][j]) - mx);
        sum += t;
        e[j] = (short)bf(t);
      }
      *(bf16x8*)(rowp + ((g * 128 + l2 * 8) ^ rx)) = e;  // unnormalized exp
    }
#pragma unroll
    for (int o = 1; o < 16; o <<= 1) sum += __shfl_xor(sum, o);
    if (l2 == 0) invbuf[r2] = 1.f / sum;
  }
  __syncthreads();   // exp-P + invbuf visible; V0 drained

  // ---- P3: O = P.V^T; wave-private d 16-rows, 16 chunks of 64 kv ----
  f32x4 oacc = {};
  {
    for (int c = 0; c < 16; ++c) {
      if (c < 15) {
        const u16* nsrc = vbase + (size_t)srow8 * 1024 + (c + 1) * 64;
        u16* ndst = kw + ((c + 1) & 1) * 1024;
        gload16(nsrc, ndst);
        gload16(nsrc + 8 * 1024, ndst + 512);
        asm volatile("s_waitcnt vmcnt(2)" ::: "memory");
      } else {
        asm volatile("s_waitcnt vmcnt(0)" ::: "memory");
      }
      __builtin_amdgcn_sched_barrier(0);
      const u16* vb = kw + (c & 1) * 1024;
      const int vr = l15;
#pragma unroll
      for (int ks = 0; ks < 2; ++ks) {
        const int gg = ks * 4 + l4;
        bf16x8 vf = *(const bf16x8*)(vb + vr * 64 + ((gg ^ (vr & 7)) << 3));
        const int e = c * 64 + ks * 32 + l4 * 8;
        bf16x8 pf = *(const bf16x8*)(sc + l15 * 1024 + (e ^ ((l15 & 7) << 3)));
        oacc = mfma16(pf, vf, oacc);
      }
    }
  }

  // ---- tail: all global stores ----
#pragma unroll
  for (int i = 0; i < 4; ++i) {
    float iv = invbuf[l4 * 4 + i];
    aout[(size_t)(b * 1024 + q0 + l4 * 4 + i) * 1024 + h * 64 + wave * 16 + l15] =
        bf(oacc[i] * iv);
  }
  // attn_out: NT full-line stores (v10 A/B: plain = +94us L2 thrash)
#pragma unroll
  for (int it = 0; it < 16; ++it) {
    const int ebase = (tid * 4) ^ ((it & 7) << 3);
    u16x4 p = *(const u16x4*)(sc + it * 1024 + ebase);
    const float iv = invbuf[it];
    f32x4 w;
    w[0] = b2f((short)p.x) * iv;
    w[1] = b2f((short)p.y) * iv;
    w[2] = b2f((short)p.z) * iv;
    w[3] = b2f((short)p.w) * iv;
    __builtin_nontemporal_store(
        w, (f32x4*)(attn_out + ((size_t)bh * 1024 + q0 + it) * 1024 + tid * 4));
  }
}

// ---------------- LayerNorm: one wave per row ----------------
__global__ __launch_bounds__(256) void k_ln(const float* __restrict__ y,
                                            const float* __restrict__ g,
                                            const float* __restrict__ be,
                                            float* __restrict__ o) {
  const int lane = threadIdx.x & 63;
  const int wave = threadIdx.x >> 6;
  size_t row = (size_t)blockIdx.x * 4 + wave;
  const float* yr = y + row * 1024;
  float4 v[4];
  float s = 0.f, sq = 0.f;
#pragma unroll
  for (int i = 0; i < 4; ++i) {
    v[i] = *(const float4*)(yr + i * 256 + lane * 4);
    s += v[i].x + v[i].y + v[i].z + v[i].w;
    sq += v[i].x * v[i].x + v[i].y * v[i].y + v[i].z * v[i].z + v[i].w * v[i].w;
  }
#pragma unroll
  for (int off = 1; off < 64; off <<= 1) {
    s += __shfl_xor(s, off);
    sq += __shfl_xor(sq, off);
  }
  float mu = s * (1.f / 1024.f);
  float var = sq * (1.f / 1024.f) - mu * mu;
  float rs = rsqrtf(fmaxf(var, 0.f) + 1e-5f);
  float* orow = o + row * 1024;
#pragma unroll
  for (int i = 0; i < 4; ++i) {
    int c = i * 256 + lane * 4;
    float4 gg = *(const float4*)(g + c);
    float4 bb = *(const float4*)(be + c);
    float4 rr;
    rr.x = (v[i].x - mu) * rs * gg.x + bb.x;
    rr.y = (v[i].y - mu) * rs * gg.y + bb.y;
    rr.z = (v[i].z - mu) * rs * gg.z + bb.z;
    rr.w = (v[i].w - mu) * rs * gg.w + bb.w;
    *(float4*)(orow + c) = rr;
  }
}

extern "C" void kernel_launch(void* const* d_in, const int* in_sizes, int n_in,
                              void* d_out, int out_size, void* d_ws, size_t ws_size,
                              hipStream_t stream) {
  const float* x = (const float*)d_in[0];
  const float* Wq = (const float*)d_in[1];
  const float* bq = (const float*)d_in[2];
  const float* Wk = (const float*)d_in[3];
  const float* bk = (const float*)d_in[4];
  const float* Wv = (const float*)d_in[5];
  const float* bv = (const float*)d_in[6];
  const float* pb = (const float*)d_in[7];
  const float* Wo = (const float*)d_in[8];
  const float* bo = (const float*)d_in[9];
  const float* gamma = (const float*)d_in[10];
  const float* beta = (const float*)d_in[11];

  char* ws = (char*)d_ws;
  u16* xb = (u16*)(ws);                  // [0,16) MB; reused as aows after attn input consumed
  u16* aows = (u16*)(ws);
  u16* wqT = (u16*)(ws + (16u << 20));
  u16* wkT = (u16*)(ws + (18u << 20));
  u16* wvT = (u16*)(ws + (20u << 20));
  u16* woT = (u16*)(ws + (22u << 20));
  u16* qws = (u16*)(ws + (24u << 20));
  u16* kws = (u16*)(ws + (40u << 20));
  u16* vtws = (u16*)(ws + (56u << 20));
  float* yws = (float*)(ws + (72u << 20));
  // pbb overlays the first 2MB of yws: pbb is consumed by k_attn; yws is only
  // written by k_gemm_o AFTER k_attn completes (stream-ordered). No conflict.
  u16* pbb = (u16*)(ws + (72u << 20));

  float* out_ln = (float*)d_out;
  float* out_attn = out_ln + (size_t)Mm * Dd;

  k_prep<<<13312, 256, 0, stream>>>(x, xb, pb, pbb, Wq, Wk, Wv, Wo,
                                    wqT, wkT, wvT, woT);
  k_gemm_qkv<<<dim3(8, 64, 3), 256, 0, stream>>>(xb, wqT, wkT, wvT,
                                                 bq, bk, bv, qws, kws, vtws);
  k_attn<<<8192, 256, 0, stream>>>(qws, kws, vtws, pbb, out_attn, aows);
  k_gemm_o<<<dim3(8, 64), 256, 0, stream>>>(aows, woT, bo, x, yws);
  k_ln<<<2048, 256, 0, stream>>>(yws, gamma, beta, out_ln);
}

// Round 13
// 310.032 us; speedup vs baseline: 1.3193x; 1.0071x over previous
//
#include <hip/hip_runtime.h>
#include <hip/hip_bf16.h>
#include <stdint.h>
#include <stddef.h>

#define DI __device__ __forceinline__

typedef unsigned short u16;
typedef float f32x4 __attribute__((ext_vector_type(4)));
typedef short bf16x8 __attribute__((ext_vector_type(8)));
typedef u16 u16x4 __attribute__((ext_vector_type(4)));

constexpr int Mm = 8192;
constexpr int Dd = 1024;
constexpr float LOG2E = 1.44269504088896f;

DI u16 bf(float f) {
  __hip_bfloat16 h = __float2bfloat16(f);
  return *reinterpret_cast<u16*>(&h);
}

DI float b2f(short s) {
  union { float f; unsigned u; } v;
  v.u = ((unsigned)(unsigned short)s) << 16;
  return v.f;
}

DI f32x4 mfma16(bf16x8 a, bf16x8 b, f32x4 c) {
  return __builtin_amdgcn_mfma_f32_16x16x32_bf16(a, b, c, 0, 0, 0);
}

DI void gload16(const u16* g, u16* l) {
  __builtin_amdgcn_global_load_lds(
      (const __attribute__((address_space(1))) void*)(g),
      (__attribute__((address_space(3))) void*)(l), 16, 0, 0);
}

// ---------------- prep: cvt x | pb->bf16*log2e | transpose 4 W ----------------
__global__ __launch_bounds__(256) void k_prep(const float* __restrict__ x,
                                              u16* __restrict__ xb,
                                              const float* __restrict__ pb,
                                              u16* __restrict__ pbb,
                                              const float* __restrict__ W0,
                                              const float* __restrict__ W1,
                                              const float* __restrict__ W2,
                                              const float* __restrict__ W3,
                                              u16* __restrict__ T0,
                                              u16* __restrict__ T1,
                                              u16* __restrict__ T2,
                                              u16* __restrict__ T3) {
  __shared__ float t[32][33];
  const int bid = blockIdx.x;
  const int tid = threadIdx.x;
  if (bid < 8192) {
    size_t i = (size_t)bid * 256 + tid;
    float4 v = *(const float4*)(x + i * 4);
    u16x4 r;
    r.x = bf(v.x); r.y = bf(v.y); r.z = bf(v.z); r.w = bf(v.w);
    *(u16x4*)(xb + i * 4) = r;
  } else if (bid < 9216) {
    size_t i = (size_t)(bid - 8192) * 256 + tid;
    float4 v = *(const float4*)(pb + i * 4);
    u16x4 r;
    r.x = bf(v.x * LOG2E); r.y = bf(v.y * LOG2E);
    r.z = bf(v.z * LOG2E); r.w = bf(v.w * LOG2E);
    *(u16x4*)(pbb + i * 4) = r;
  } else {
    const int tt = bid - 9216;
    const int z = tt >> 10;
    const int rem = tt & 1023;
    const float* W;
    u16* T;
    switch (z) {
      case 0: W = W0; T = T0; break;
      case 1: W = W1; T = T1; break;
      case 2: W = W2; T = T2; break;
      default: W = W3; T = T3; break;
    }
    const int bx = (rem & 31) * 32;
    const int by = (rem >> 5) * 32;
    const int tx = tid & 31, ty = tid >> 5;
#pragma unroll
    for (int i = 0; i < 4; ++i)
      t[ty + i * 8][tx] = W[(size_t)(bx + ty + i * 8) * 1024 + by + tx];
    __syncthreads();
#pragma unroll
    for (int i = 0; i < 4; ++i)
      T[(size_t)(by + ty + i * 8) * 1024 + bx + tx] = bf(t[tx][ty + i * 8]);
  }
}

// ---------------- QKV mega-GEMM: z=0 Q, z=1 K, z=2 V(transposed) ----------------
__global__ __launch_bounds__(256) void k_gemm_qkv(const u16* __restrict__ A,
                                                  const u16* __restrict__ wqT,
                                                  const u16* __restrict__ wkT,
                                                  const u16* __restrict__ wvT,
                                                  const float* __restrict__ bq,
                                                  const float* __restrict__ bk,
                                                  const float* __restrict__ bv,
                                                  u16* __restrict__ qo,
                                                  u16* __restrict__ ko,
                                                  u16* __restrict__ vo) {
  __shared__ __align__(16) u16 smem[2 * 128 * 64];
  u16* As = smem;
  u16* Bs = smem + 128 * 64;
  const int mode = blockIdx.z;
  const u16* WT = mode == 0 ? wqT : (mode == 1 ? wkT : wvT);
  const float* bias = mode == 0 ? bq : (mode == 1 ? bk : bv);
  const int tid = threadIdx.x;
  const int lane = tid & 63;
  const int wave = tid >> 6;
  const int brow = blockIdx.y * 128;
  const int bcol = blockIdx.x * 128;
  const int wr = (wave >> 1) * 64;
  const int wc = (wave & 1) * 64;
  const int l15 = lane & 15, l4 = lane >> 4;

  f32x4 acc[4][4] = {};
  const int crow0 = tid >> 3;
  const int kpos = (tid & 7) * 8;

  for (int t = 0; t < 16; ++t) {
    const int k0 = t * 64;
#pragma unroll
    for (int r = 0; r < 4; ++r) {
      int crow = r * 32 + crow0;
      u16* ldsbase_a = As + ((r * 256 + wave * 64) << 3);
      u16* ldsbase_b = Bs + ((r * 256 + wave * 64) << 3);
      gload16(A + (size_t)(brow + crow) * 1024 + k0 + kpos, ldsbase_a);
      gload16(WT + (size_t)(bcol + crow) * 1024 + k0 + kpos, ldsbase_b);
    }
    __syncthreads();
#pragma unroll
    for (int kk = 0; kk < 2; ++kk) {
      bf16x8 af[4], bg[4];
      const int kb = kk * 32 + l4 * 8;
#pragma unroll
      for (int mt = 0; mt < 4; ++mt)
        af[mt] = *(const bf16x8*)(As + (wr + mt * 16 + l15) * 64 + kb);
#pragma unroll
      for (int nt = 0; nt < 4; ++nt)
        bg[nt] = *(const bf16x8*)(Bs + (wc + nt * 16 + l15) * 64 + kb);
#pragma unroll
      for (int mt = 0; mt < 4; ++mt)
#pragma unroll
        for (int nt = 0; nt < 4; ++nt)
          acc[mt][nt] = mfma16(af[mt], bg[nt], acc[mt][nt]);
    }
    __syncthreads();
  }

  if (mode == 2) {
#pragma unroll
    for (int nt = 0; nt < 4; ++nt) {
      int dl = wc + nt * 16 + l15;
      float bvv = bias[bcol + dl];
#pragma unroll
      for (int mt = 0; mt < 4; ++mt) {
        int s4 = wr + mt * 16 + l4 * 4;
        u16x4 pk;
        pk.x = bf(acc[mt][nt][0] + bvv);
        pk.y = bf(acc[mt][nt][1] + bvv);
        pk.z = bf(acc[mt][nt][2] + bvv);
        pk.w = bf(acc[mt][nt][3] + bvv);
        *(u16x4*)(smem + dl * 128 + (s4 ^ ((dl & 7) << 3))) = pk;
      }
    }
    __syncthreads();
    const int bb = brow >> 10;
    const int seq0 = brow & 1023;
    const int chunk = tid & 15;
#pragma unroll
    for (int p = 0; p < 8; ++p) {
      int dl = p * 16 + (tid >> 4);
      bf16x8 v = *(const bf16x8*)(smem + dl * 128 + ((chunk * 8) ^ ((dl & 7) << 3)));
      *(bf16x8*)(vo + ((size_t)bb * 1024 + bcol + dl) * 1024 + seq0 + chunk * 8) = v;
    }
    return;
  }

  u16* outp = mode == 0 ? qo : ko;
  const float scale = mode == 0 ? (0.125f * LOG2E) : 1.0f;
#pragma unroll
  for (int nt = 0; nt < 4; ++nt) {
    int gc = bcol + wc + nt * 16 + l15;
    float bvv = bias[gc];
#pragma unroll
    for (int mt = 0; mt < 4; ++mt) {
#pragma unroll
      for (int i = 0; i < 4; ++i) {
        int gm = brow + wr + mt * 16 + l4 * 4 + i;
        outp[(size_t)gm * 1024 + gc] = bf((acc[mt][nt][i] + bvv) * scale);
      }
    }
  }
}

// ---------------- O-proj GEMM: f32 acc+bias+resid ----------------
__global__ __launch_bounds__(256) void k_gemm_o(const u16* __restrict__ A,
                                                const u16* __restrict__ WT,
                                                const float* __restrict__ bias,
                                                const float* __restrict__ resid,
                                                float* __restrict__ outp) {
  __shared__ __align__(16) u16 smem[2 * 128 * 64];
  u16* As = smem;
  u16* Bs = smem + 128 * 64;
  const int tid = threadIdx.x;
  const int lane = tid & 63;
  const int wave = tid >> 6;
  const int brow = blockIdx.y * 128;
  const int bcol = blockIdx.x * 128;
  const int wr = (wave >> 1) * 64;
  const int wc = (wave & 1) * 64;
  const int l15 = lane & 15, l4 = lane >> 4;

  f32x4 acc[4][4] = {};
  const int crow0 = tid >> 3;
  const int kpos = (tid & 7) * 8;

  for (int t = 0; t < 16; ++t) {
    const int k0 = t * 64;
#pragma unroll
    for (int r = 0; r < 4; ++r) {
      int crow = r * 32 + crow0;
      u16* ldsbase_a = As + ((r * 256 + wave * 64) << 3);
      u16* ldsbase_b = Bs + ((r * 256 + wave * 64) << 3);
      gload16(A + (size_t)(brow + crow) * 1024 + k0 + kpos, ldsbase_a);
      gload16(WT + (size_t)(bcol + crow) * 1024 + k0 + kpos, ldsbase_b);
    }
    __syncthreads();
#pragma unroll
    for (int kk = 0; kk < 2; ++kk) {
      bf16x8 af[4], bg[4];
      const int kb = kk * 32 + l4 * 8;
#pragma unroll
      for (int mt = 0; mt < 4; ++mt)
        af[mt] = *(const bf16x8*)(As + (wr + mt * 16 + l15) * 64 + kb);
#pragma unroll
      for (int nt = 0; nt < 4; ++nt)
        bg[nt] = *(const bf16x8*)(Bs + (wc + nt * 16 + l15) * 64 + kb);
#pragma unroll
      for (int mt = 0; mt < 4; ++mt)
#pragma unroll
        for (int nt = 0; nt < 4; ++nt)
          acc[mt][nt] = mfma16(af[mt], bg[nt], acc[mt][nt]);
    }
    __syncthreads();
  }

#pragma unroll
  for (int nt = 0; nt < 4; ++nt) {
    int gc = bcol + wc + nt * 16 + l15;
    float bvv = bias[gc];
#pragma unroll
    for (int mt = 0; mt < 4; ++mt) {
#pragma unroll
      for (int i = 0; i < 4; ++i) {
        int gm = brow + wr + mt * 16 + l4 * 4 + i;
        outp[(size_t)gm * 1024 + gc] =
            acc[mt][nt][i] + bvv + resid[(size_t)gm * 1024 + gc];
      }
    }
  }
}

// ---------------- attention v13: wave-specialized post-softmax ----------------
// P1 (all 4 waves): S = K.Q^T, wave-private counted-vmcnt staging.
// P2 (all 4 waves): softmax.
// Post-P2 split: waves 0-1 -> PV (32 d-rows each, 4-gload dbuf, vmcnt(4));
//                waves 2-3 -> attn_out NT store loop (overlaps PV).
// Per-wave vmcnt counters make the split safe for the counted scheme.
__global__ __launch_bounds__(256, 3) void k_attn(const u16* __restrict__ q,
                                                 const u16* __restrict__ kk_,
                                                 const u16* __restrict__ vt,
                                                 const u16* __restrict__ pbb,
                                                 float* __restrict__ attn_out,
                                                 u16* __restrict__ aout) {
  __shared__ __align__(16) u16 sc[16 * 1024];   // 32 KB scores/P, XOR-swizzled
  __shared__ __align__(16) u16 kst[8192];       // 16 KB stage (repartitioned per phase)
  __shared__ float invbuf[16];
  const int tid = threadIdx.x;
  const int lane = tid & 63;
  const int wave = tid >> 6;        // 0..3
  const int bid = blockIdx.x;
  const int swz = (bid & 7) * 1024 + (bid >> 3);  // XCD-chunked (8192%8==0)
  const int bh = swz >> 6;          // 0..127
  const int q0 = (swz & 63) * 16;
  const int b = bh >> 4, h = bh & 15;
  const int l15 = lane & 15, l4 = lane >> 4;
  const int srow8 = (lane >> 3) & 7;
  const int sgsw = (lane & 7) ^ srow8;

  bf16x8 qf0, qf1;
  {
    const u16* qp = q + ((size_t)(b * 1024 + q0 + l15)) * 1024 + h * 64 + l4 * 8;
    qf0 = *(const bf16x8*)qp;
    qf1 = *(const bf16x8*)(qp + 32);
  }

  // ---- P1: S = K.Q^T -> sc; wave-private kv quarter, 16 chunks of 16 ----
  {
    u16* const kw = kst + wave * 2048;  // 2 x 1024 u16 dbuf
    const int kvb = wave * 256;
    const u16* kbase = kk_ + (size_t)(b * 1024 + kvb) * 1024 + h * 64 + sgsw * 8;
    gload16(kbase + (size_t)srow8 * 1024, kw);
    gload16(kbase + (size_t)(8 + srow8) * 1024, kw + 512);
    for (int c = 0; c < 16; ++c) {
      if (c < 15) {
        const u16* nsrc = kbase + (size_t)((c + 1) * 16 + srow8) * 1024;
        u16* ndst = kw + ((c + 1) & 1) * 1024;
        gload16(nsrc, ndst);
        gload16(nsrc + 8 * 1024, ndst + 512);
        asm volatile("s_waitcnt vmcnt(2)" ::: "memory");
      } else {
        asm volatile("s_waitcnt vmcnt(0)" ::: "memory");
      }
      __builtin_amdgcn_sched_barrier(0);
      const u16* kb = kw + (c & 1) * 1024;
      const int r = l15;
      bf16x8 k0 = *(const bf16x8*)(kb + r * 64 + ((l4 ^ (r & 7)) << 3));
      bf16x8 k1 = *(const bf16x8*)(kb + r * 64 + (((4 + l4) ^ (r & 7)) << 3));
      f32x4 cc = {};
      cc = mfma16(k0, qf0, cc);
      cc = mfma16(k1, qf1, cc);
      const int c4 = kvb + c * 16 + l4 * 4;
      u16x4 pk;
      pk.x = bf(cc[0]); pk.y = bf(cc[1]); pk.z = bf(cc[2]); pk.w = bf(cc[3]);
      *(u16x4*)(sc + l15 * 1024 + (c4 ^ ((l15 & 7) << 3))) = pk;
    }
  }
  __syncthreads();   // sc complete; kst dead (P1 layout)

  // PV waves (0-1) prefetch their V chunk 0 (4 x 1KB) -> lands during softmax,
  // guaranteed complete at the post-P2 barrier (vmcnt(0) drain).
  const u16* vbase2 = vt + (size_t)(b * 1024 + h * 64 + wave * 32 + srow8) * 1024 + sgsw * 8;
  u16* const kw3 = kst + wave * 4096;  // 2 x 2048 u16 dbuf (waves 0-1 only)
  if (wave < 2) {
#pragma unroll
    for (int i = 0; i < 4; ++i)
      gload16(vbase2 + (size_t)(i * 8) * 1024, kw3 + i * 512);
  }

  // ---- P2: softmax + pbb add (all waves) ----
  const int r2 = tid >> 4;
  const int l2 = tid & 15;
  {
    const int rx = (r2 & 7) << 3;
    u16* rowp = sc + r2 * 1024;
    const u16* pbrow = pbb + (size_t)(q0 + r2) * 1024 + l2 * 8;
    bf16x8 R[8];
#pragma unroll
    for (int g = 0; g < 8; ++g) {
      bf16x8 v = *(const bf16x8*)(rowp + ((g * 128 + l2 * 8) ^ rx));
      bf16x8 pv = *(const bf16x8*)(pbrow + g * 128);
      bf16x8 s;
#pragma unroll
      for (int j = 0; j < 8; ++j) s[j] = (short)bf(b2f(v[j]) + b2f(pv[j]));
      R[g] = s;
    }
    float mx = -3e38f;
#pragma unroll
    for (int g = 0; g < 8; ++g)
#pragma unroll
      for (int j = 0; j < 8; ++j) mx = fmaxf(mx, b2f(R[g][j]));
#pragma unroll
    for (int o = 1; o < 16; o <<= 1) mx = fmaxf(mx, __shfl_xor(mx, o));
    float sum = 0.f;
#pragma unroll
    for (int g = 0; g < 8; ++g) {
      bf16x8 e;
#pragma unroll
      for (int j = 0; j < 8; ++j) {
        float t = exp2f(b2f(R[g][j]) - mx);
        sum += t;
        e[j] = (short)bf(t);
      }
      *(bf16x8*)(rowp + ((g * 128 + l2 * 8) ^ rx)) = e;  // unnormalized exp
    }
#pragma unroll
    for (int o = 1; o < 16; o <<= 1) sum += __shfl_xor(sum, o);
    if (l2 == 0) invbuf[r2] = 1.f / sum;
  }
  __syncthreads();   // exp-P + invbuf visible; PV waves' V0 drained

  if (wave < 2) {
    // ---- PV waves: O = P.V^T over 32 d-rows, 16 chunks of 64 kv ----
    f32x4 oacc[2] = {};
    for (int c = 0; c < 16; ++c) {
      if (c < 15) {
        const u16* nsrc = vbase2 + (c + 1) * 64;
        u16* ndst = kw3 + ((c + 1) & 1) * 2048;
#pragma unroll
        for (int i = 0; i < 4; ++i)
          gload16(nsrc + (size_t)(i * 8) * 1024, ndst + i * 512);
        asm volatile("s_waitcnt vmcnt(4)" ::: "memory");
      } else {
        asm volatile("s_waitcnt vmcnt(0)" ::: "memory");
      }
      __builtin_amdgcn_sched_barrier(0);
      const u16* vb = kw3 + (c & 1) * 2048;
#pragma unroll
      for (int ks = 0; ks < 2; ++ks) {
        const int gg = ks * 4 + l4;
        const int e = c * 64 + ks * 32 + l4 * 8;
        bf16x8 pf = *(const bf16x8*)(sc + l15 * 1024 + (e ^ ((l15 & 7) << 3)));
#pragma unroll
        for (int dg = 0; dg < 2; ++dg) {
          const int vr = dg * 16 + l15;
          bf16x8 vf = *(const bf16x8*)(vb + vr * 64 + ((gg ^ (vr & 7)) << 3));
          oacc[dg] = mfma16(pf, vf, oacc[dg]);
        }
      }
    }
#pragma unroll
    for (int dg = 0; dg < 2; ++dg)
#pragma unroll
      for (int i = 0; i < 4; ++i) {
        float iv = invbuf[l4 * 4 + i];
        aout[(size_t)(b * 1024 + q0 + l4 * 4 + i) * 1024 + h * 64 + wave * 32 +
             dg * 16 + l15] = bf(oacc[dg][i] * iv);
      }
  } else {
    // ---- store waves: attn_out NT full-line stores (overlaps PV) ----
    const int tid2 = tid - 128;  // 0..127
#pragma unroll
    for (int it = 0; it < 32; ++it) {
      const int row = it >> 1;
      const int col4 = (it & 1) * 128 + tid2;
      const int ebase = (col4 * 4) ^ ((row & 7) << 3);
      u16x4 p = *(const u16x4*)(sc + row * 1024 + ebase);
      const float iv = invbuf[row];
      f32x4 w;
      w[0] = b2f((short)p.x) * iv;
      w[1] = b2f((short)p.y) * iv;
      w[2] = b2f((short)p.z) * iv;
      w[3] = b2f((short)p.w) * iv;
      __builtin_nontemporal_store(
          w, (f32x4*)(attn_out + ((size_t)bh * 1024 + q0 + row) * 1024 + col4 * 4));
    }
  }
}

// ---------------- LayerNorm: one wave per row ----------------
__global__ __launch_bounds__(256) void k_ln(const float* __restrict__ y,
                                            const float* __restrict__ g,
                                            const float* __restrict__ be,
                                            float* __restrict__ o) {
  const int lane = threadIdx.x & 63;
  const int wave = threadIdx.x >> 6;
  size_t row = (size_t)blockIdx.x * 4 + wave;
  const float* yr = y + row * 1024;
  float4 v[4];
  float s = 0.f, sq = 0.f;
#pragma unroll
  for (int i = 0; i < 4; ++i) {
    v[i] = *(const float4*)(yr + i * 256 + lane * 4);
    s += v[i].x + v[i].y + v[i].z + v[i].w;
    sq += v[i].x * v[i].x + v[i].y * v[i].y + v[i].z * v[i].z + v[i].w * v[i].w;
  }
#pragma unroll
  for (int off = 1; off < 64; off <<= 1) {
    s += __shfl_xor(s, off);
    sq += __shfl_xor(sq, off);
  }
  float mu = s * (1.f / 1024.f);
  float var = sq * (1.f / 1024.f) - mu * mu;
  float rs = rsqrtf(fmaxf(var, 0.f) + 1e-5f);
  float* orow = o + row * 1024;
#pragma unroll
  for (int i = 0; i < 4; ++i) {
    int c = i * 256 + lane * 4;
    float4 gg = *(const float4*)(g + c);
    float4 bb = *(const float4*)(be + c);
    float4 rr;
    rr.x = (v[i].x - mu) * rs * gg.x + bb.x;
    rr.y = (v[i].y - mu) * rs * gg.y + bb.y;
    rr.z = (v[i].z - mu) * rs * gg.z + bb.z;
    rr.w = (v[i].w - mu) * rs * gg.w + bb.w;
    *(float4*)(orow + c) = rr;
  }
}

extern "C" void kernel_launch(void* const* d_in, const int* in_sizes, int n_in,
                              void* d_out, int out_size, void* d_ws, size_t ws_size,
                              hipStream_t stream) {
  const float* x = (const float*)d_in[0];
  const float* Wq = (const float*)d_in[1];
  const float* bq = (const float*)d_in[2];
  const float* Wk = (const float*)d_in[3];
  const float* bk = (const float*)d_in[4];
  const float* Wv = (const float*)d_in[5];
  const float* bv = (const float*)d_in[6];
  const float* pb = (const float*)d_in[7];
  const float* Wo = (const float*)d_in[8];
  const float* bo = (const float*)d_in[9];
  const float* gamma = (const float*)d_in[10];
  const float* beta = (const float*)d_in[11];

  char* ws = (char*)d_ws;
  u16* xb = (u16*)(ws);
  u16* aows = (u16*)(ws);
  u16* wqT = (u16*)(ws + (16u << 20));
  u16* wkT = (u16*)(ws + (18u << 20));
  u16* wvT = (u16*)(ws + (20u << 20));
  u16* woT = (u16*)(ws + (22u << 20));
  u16* qws = (u16*)(ws + (24u << 20));
  u16* kws = (u16*)(ws + (40u << 20));
  u16* vtws = (u16*)(ws + (56u << 20));
  float* yws = (float*)(ws + (72u << 20));
  u16* pbb = (u16*)(ws + (72u << 20));  // overlays yws head; dead before gemm_o writes

  float* out_ln = (float*)d_out;
  float* out_attn = out_ln + (size_t)Mm * Dd;

  k_prep<<<13312, 256, 0, stream>>>(x, xb, pb, pbb, Wq, Wk, Wv, Wo,
                                    wqT, wkT, wvT, woT);
  k_gemm_qkv<<<dim3(8, 64, 3), 256, 0, stream>>>(xb, wqT, wkT, wvT,
                                                 bq, bk, bv, qws, kws, vtws);
  k_attn<<<8192, 256, 0, stream>>>(qws, kws, vtws, pbb, out_attn, aows);
  k_gemm_o<<<dim3(8, 64), 256, 0, stream>>>(aows, woT, bo, x, yws);
  k_ln<<<2048, 256, 0, stream>>>(yws, gamma, beta, out_ln);
}